// Round 7
// baseline (270.778 us; speedup 1.0000x reference)
//
#include <hip/hip_runtime.h>
#include <math.h>
#include <stdint.h>

// Problem constants
#define D 768
#define S 2048
#define B_ 2
#define NROWS 4096   // B_*S
#define H 12
#define HD 64
#define R_ 16

typedef _Float16 half_t;
typedef _Float16 half8 __attribute__((ext_vector_type(8)));
typedef _Float16 half4 __attribute__((ext_vector_type(4)));
typedef float floatx4 __attribute__((ext_vector_type(4)));

#define MFMA32(a, b, c) __builtin_amdgcn_mfma_f32_16x16x32_f16(a, b, c, 0, 0, 0)
#define EXP2F(x) __builtin_amdgcn_exp2f(x)

#define SWAIT(N) __builtin_amdgcn_s_waitcnt(0x0F70 | (N))
#define SBAR() __builtin_amdgcn_s_barrier()
#define SETPRIO(N) __builtin_amdgcn_s_setprio(N)

// global -> LDS async DMA, 16B per lane; lane i lands at base + 16*i.
__device__ __forceinline__ void gl_lds16(const void* gp, half_t* lp) {
  __builtin_amdgcn_global_load_lds(
      (const __attribute__((address_space(1))) void*)(gp),
      (__attribute__((address_space(3))) void*)(lp), 16, 0, 0);
}

// V^T tiled-fragment layout ("vt2"): per head bh = b*H+h, per 64-token block
// kb (32 blocks): 4096 halfs = groups (ud 0..3, h2 0..1) x 512 halfs; lane
// (lq,lr) holds 8 halfs: V[kb*64+32*h2+lq*4+{0..3}][ud*16+lr] ++
//                        V[kb*64+32*h2+16+lq*4+{0..3}][ud*16+lr].

// ---------------------------------------------------------------------------
// Fused prep (round-6 verified): convert q,k,v + Wo; LDS-staged M-build.
// ---------------------------------------------------------------------------
__global__ __launch_bounds__(256) void prep_kernel(
    const float* __restrict__ q, const float* __restrict__ k,
    const float* __restrict__ v, half_t* __restrict__ xq,
    half_t* __restrict__ xk, half_t* __restrict__ xv,
    const float* __restrict__ Wq, const float* __restrict__ Aq,
    const float* __restrict__ Wk, const float* __restrict__ Ak,
    const float* __restrict__ Wv, const float* __restrict__ Av,
    const float* __restrict__ Wo, half_t* __restrict__ Mq,
    half_t* __restrict__ Mk, half_t* __restrict__ Mv,
    half_t* __restrict__ Mo) {
  __shared__ float4 As[3072];  // 48KB (used by M-build blocks only)
  const int bid = blockIdx.x;
  const int tid = threadIdx.x;

  if (bid < 2304) {
    const int y = bid / 768;
    const float* x = (y == 0) ? q : (y == 1) ? k : v;
    half_t* o = (y == 0) ? xq : (y == 1) ? xk : xv;
    const int base = (bid - y * 768) * 4096;
#pragma unroll
    for (int c = 0; c < 4; ++c) {
      int i = base + (tid + 256 * c) * 4;
      float4 vv = *reinterpret_cast<const float4*>(x + i);
      half_t tmp[4] = {(half_t)vv.x, (half_t)vv.y, (half_t)vv.z, (half_t)vv.w};
      *reinterpret_cast<uint64_t*>(o + i) = *reinterpret_cast<uint64_t*>(tmp);
    }
  } else if (bid < 2448) {
    const int base = (bid - 2304) * 4096;
#pragma unroll
    for (int c = 0; c < 4; ++c) {
      int i = base + (tid + 256 * c) * 4;
      float4 vv = *reinterpret_cast<const float4*>(Wo + i);
      half_t tmp[4] = {(half_t)vv.x, (half_t)vv.y, (half_t)vv.z, (half_t)vv.w};
      *reinterpret_cast<uint64_t*>(Mo + i) = *reinterpret_cast<uint64_t*>(tmp);
    }
  } else {
    const int u = bid - 2448;
    const int y = u / 192;           // 0..2 -> q,k,v
    const int jb = u - y * 192;      // j-band
    const float* W = (y == 0) ? Wq : (y == 1) ? Wk : Wv;
    const float* A = (y == 0) ? Aq : (y == 1) ? Ak : Av;
    half_t* M = (y == 0) ? Mq : (y == 1) ? Mk : Mv;

    // Stage A[768][16] f32 into LDS, coalesced.
#pragma unroll
    for (int c = 0; c < 12; ++c)
      As[tid + 256 * c] =
          *reinterpret_cast<const float4*>(A + (tid + 256 * c) * 4);
    __syncthreads();

    const int j0 = jb * 4;
    float4 aj[4][4];
#pragma unroll
    for (int jj = 0; jj < 4; ++jj)
#pragma unroll
      for (int qq = 0; qq < 4; ++qq) aj[jj][qq] = As[(j0 + jj) * 4 + qq];

#pragma unroll
    for (int c = 0; c < 3; ++c) {
      const int kk = tid + 256 * c;
      float4 ak[4];
#pragma unroll
      for (int qq = 0; qq < 4; ++qq) ak[qq] = As[kk * 4 + qq];
#pragma unroll
      for (int jj = 0; jj < 4; ++jj) {
        float s = 0.f;
#pragma unroll
        for (int qq = 0; qq < 4; ++qq)
          s += ak[qq].x * aj[jj][qq].x + ak[qq].y * aj[jj][qq].y +
               ak[qq].z * aj[jj][qq].z + ak[qq].w * aj[jj][qq].w;
        const int idx = (j0 + jj) * D + kk;
        M[idx] = (half_t)(W[idx] + 4.0f * s);
      }
    }
  }
}

// ---------------------------------------------------------------------------
// QKV GEMM (fp16 in/out): C[n][j] = sum_k X[n][k]*Mh[j][k] + bias[j].
// 128x128 tile, 4 waves (2x2, 64x64 each), BK=32, 3-stage DMA pipeline
// (48KB LDS -> 3 blocks/CU), raw barrier + counted vmcnt(4) per iter.
// XCD-chunked block swizzle (576 = 8 x 72).
// z==2 writes V output in vt2 layout via direct coalesced half4 stores.
// ---------------------------------------------------------------------------
__global__ __launch_bounds__(256) void gemm_qkv_kernel(
    const half_t* __restrict__ x0, const half_t* __restrict__ x1,
    const half_t* __restrict__ x2, const half_t* __restrict__ m0,
    const half_t* __restrict__ m1, const half_t* __restrict__ m2,
    const float* __restrict__ b0, const float* __restrict__ b1,
    const float* __restrict__ b2, half_t* __restrict__ o0,
    half_t* __restrict__ o1, half_t* __restrict__ o2) {
  constexpr int AG = 8;        // A groups (128 rows x 32 k)
  constexpr int G = 16;        // + 8 B groups (128 cols x 32 k)
  constexpr int PB = G * 512;  // 8192 halfs = 16KB per stage
  __shared__ __align__(16) half_t smem[3 * PB];  // 48KB

  // Bijective XCD-chunk swizzle: linear id -> (xcd owns contiguous 72).
  int lin = blockIdx.x + 6 * (blockIdx.y + 32 * blockIdx.z);
  lin = (lin & 7) * 72 + (lin >> 3);
  const int z = lin / 192;
  const int rem = lin - z * 192;
  const int by = rem / 6;
  const int bx = rem - by * 6;

  const half_t* X = (z == 0) ? x0 : (z == 1) ? x1 : x2;
  const half_t* M = (z == 0) ? m0 : (z == 1) ? m1 : m2;
  const float* bias = (z == 0) ? b0 : (z == 1) ? b1 : b2;
  half_t* Out = (z == 0) ? o0 : (z == 1) ? o1 : o2;

  const int tid = threadIdx.x;
  const int lane = tid & 63;
  const int wv = tid >> 6;
  const int lr = lane & 15;
  const int lq = lane >> 4;
  const int row0 = by * 128;
  const int j0 = bx * 128;
  const int wr = wv >> 1;  // wave row 0..1
  const int wc = wv & 1;   // wave col 0..1

  floatx4 acc[4][4] = {};

#define GSTAGE(soff, k0)                                                      \
  do {                                                                        \
    _Pragma("unroll") for (int gi = 0; gi < 4; ++gi) {                        \
      int g = wv * 4 + gi;                                                    \
      if (g < AG) {                                                           \
        gl_lds16(X + (size_t)(row0 + g * 16 + lr) * D + (k0) + lq * 8,        \
                 smem + (soff) + g * 512);                                    \
      } else {                                                                \
        gl_lds16(M + (size_t)(j0 + (g - AG) * 16 + lr) * D + (k0) + lq * 8,   \
                 smem + (soff) + g * 512);                                    \
      }                                                                       \
    }                                                                         \
  } while (0)

  GSTAGE(0, 0);
  GSTAGE(PB, 32);
  SWAIT(4);
  SBAR();

  int co = 0, so = 2 * PB;
  for (int it = 0; it < D / 32; ++it) {
    if (it + 2 < D / 32) GSTAGE(so, (it + 2) * 32);
    const half_t* Ab = smem + co;
    const half_t* Bb = Ab + AG * 512;
    half8 af[4], bf[4];
#pragma unroll
    for (int t = 0; t < 4; ++t)
      af[t] = *reinterpret_cast<const half8*>(
          &Ab[((wr * 4 + t) * 64 + lane) * 8]);
#pragma unroll
    for (int u = 0; u < 4; ++u)
      bf[u] = *reinterpret_cast<const half8*>(
          &Bb[((wc * 4 + u) * 64 + lane) * 8]);
#pragma unroll
    for (int t = 0; t < 4; ++t)
#pragma unroll
      for (int u = 0; u < 4; ++u) acc[t][u] = MFMA32(af[t], bf[u], acc[t][u]);
    if (it + 2 < D / 32) SWAIT(4); else SWAIT(0);
    SBAR();
    co += PB; if (co == 3 * PB) co = 0;
    so += PB; if (so == 3 * PB) so = 0;
  }
#undef GSTAGE

  float bv[4];
#pragma unroll
  for (int u = 0; u < 4; ++u) bv[u] = bias[j0 + (wc * 4 + u) * 16 + lr];

  if (z == 2) {
    // Direct vt2 stores from registers. Rows span 2 kb-blocks: kb = wr.
    const int bb = row0 >> 11;
    const int kb0 = (row0 & 2047) >> 6;
#pragma unroll
    for (int t = 0; t < 4; ++t) {
#pragma unroll
      for (int u = 0; u < 4; ++u) {
        int gc = j0 + (wc * 4 + u) * 16 + lr;
        int hh = gc >> 6;
        int ud = (gc & 63) >> 4;
        half4 hv;
#pragma unroll
        for (int r = 0; r < 4; ++r) hv[r] = (half_t)(acc[t][u][r] + bv[u]);
        size_t addr = ((size_t)(bb * H + hh) * HD) * S +
                      (size_t)(kb0 + wr) * 4096 +
                      (ud * 2 + ((t >> 1) & 1)) * 512 + lane * 8 + (t & 1) * 4;
        *reinterpret_cast<half4*>(&Out[addr]) = hv;
      }
    }
    return;
  }

#pragma unroll
  for (int t = 0; t < 4; ++t) {
#pragma unroll
    for (int u = 0; u < 4; ++u) {
#pragma unroll
      for (int r = 0; r < 4; ++r) {
        int gr = row0 + (wr * 4 + t) * 16 + lq * 4 + r;
        int gc = j0 + (wc * 4 + u) * 16 + lr;
        Out[(size_t)gr * D + gc] = (half_t)(acc[t][u][r] + bv[u]);
      }
    }
  }
}

// ---------------------------------------------------------------------------
// Out-projection GEMM (fp16 in, fp32 out): 64x64 tile, 4 waves (2x2),
// 3-stage DMA pipeline (48KB LDS), raw barrier + vmcnt(4) per iter.
// + XCD-chunked swizzle (768 = 8 x 96).
// ---------------------------------------------------------------------------
__global__ __launch_bounds__(256) void gemm_o_kernel(
    const half_t* __restrict__ Xh, const half_t* __restrict__ M,
    const float* __restrict__ bias, float* __restrict__ Out) {
  constexpr int AG = 8;        // A groups (64 rows)
  constexpr int G = 16;        // + 8 B groups (64 cols)
  constexpr int PB = G * 512;  // 8192 halfs = 16KB per stage
  __shared__ __align__(16) half_t smem[3 * PB];  // 48KB

  int lin = blockIdx.x + 12 * blockIdx.y;
  lin = (lin & 7) * 96 + (lin >> 3);
  const int bx = lin % 12;
  const int byy = lin / 12;

  const int tid = threadIdx.x;
  const int lane = tid & 63;
  const int wv = tid >> 6;
  const int lr = lane & 15;
  const int lq = lane >> 4;
  const int row0 = byy * 64;
  const int j0 = bx * 64;
  const int wr = wv >> 1;  // wave row 0..1
  const int wc = wv & 1;   // wave col 0..1

  floatx4 acc[2][2] = {};

#define GSTAGE(soff, k0)                                                       \
  do {                                                                         \
    _Pragma("unroll") for (int gi = 0; gi < 4; ++gi) {                         \
      int g = wv * 4 + gi;                                                     \
      if (g < AG) {                                                            \
        int t = g >> 1, c = g & 1;                                             \
        gl_lds16(                                                              \
            Xh + (size_t)(row0 + t * 16 + lr) * D + (k0) + c * 32 + lq * 8,    \
            smem + (soff) + g * 512);                                          \
      } else {                                                                 \
        int g2 = g - AG;                                                       \
        int u = g2 >> 1, c = g2 & 1;                                           \
        gl_lds16(                                                              \
            M + (size_t)(j0 + u * 16 + lr) * D + (k0) + c * 32 + lq * 8,       \
            smem + (soff) + AG * 512 + g2 * 512);                              \
      }                                                                        \
    }                                                                          \
  } while (0)

  GSTAGE(0, 0);
  GSTAGE(PB, 64);
  SWAIT(4);
  SBAR();

  int co = 0, so = 2 * PB;
  for (int it = 0; it < D / 64; ++it) {
    if (it + 2 < D / 64) GSTAGE(so, (it + 2) * 64);
    const half_t* Ab = smem + co;
    const half_t* Bb = Ab + AG * 512;
#pragma unroll
    for (int c = 0; c < 2; ++c) {
      half8 af[2], bf[2];
#pragma unroll
      for (int t = 0; t < 2; ++t)
        af[t] = *reinterpret_cast<const half8*>(
            &Ab[(((wr * 2 + t) * 2 + c) * 64 + lane) * 8]);
#pragma unroll
      for (int u = 0; u < 2; ++u)
        bf[u] = *reinterpret_cast<const half8*>(
            &Bb[(((wc * 2 + u) * 2 + c) * 64 + lane) * 8]);
#pragma unroll
      for (int t = 0; t < 2; ++t)
#pragma unroll
        for (int u = 0; u < 2; ++u) acc[t][u] = MFMA32(af[t], bf[u], acc[t][u]);
    }
    if (it + 2 < D / 64) SWAIT(4); else SWAIT(0);
    SBAR();
    co += PB; if (co == 3 * PB) co = 0;
    so += PB; if (so == 3 * PB) so = 0;
  }
#undef GSTAGE

  float bv[2];
#pragma unroll
  for (int u = 0; u < 2; ++u) bv[u] = bias[j0 + (wc * 2 + u) * 16 + lr];
#pragma unroll
  for (int t = 0; t < 2; ++t) {
#pragma unroll
    for (int u = 0; u < 2; ++u) {
#pragma unroll
      for (int r = 0; r < 4; ++r) {
        int gr = row0 + (wr * 2 + t) * 16 + lq * 4 + r;
        int gc = j0 + (wc * 2 + u) * 16 + lr;
        Out[(size_t)gr * D + gc] = acc[t][u][r] + bv[u];
      }
    }
  }
}

// ---------------------------------------------------------------------------
// Flash attention, in-block split-K, SOFTWARE-PIPELINED (T15 retry).
// Round-4's schedule (numerically verified) with the double-buffered state
// held in INDIVIDUALLY-NAMED scalar variables (sA00..sB11 floatx4,
// vA0..vB3 half8) — no arrays, so the register allocator cannot demote
// them to scratch (round-4's failure: VGPR=84 + ~19MB scratch traffic).
// Est. ~150 VGPR < 168 cap of launch_bounds(256,3) -> 3 blocks/CU kept.
// Per iteration: QK^T(tile t) runs while exp+PV of tile t-1 consumes the
// held registers — breaks the ~600-cyc serial ds_read->QK->exp->PV chain
// that pins per-tile cost at 1088 cyc/CU across rounds 0-2.
// 3-stage DMA pipeline (48KB LDS), raw barrier + counted vmcnt(4)/iter.
// Partials additive; k'-half merge via LDS at the end.
// XCD-chunked swizzle (768 = 8 x 96).
// ---------------------------------------------------------------------------
__global__ __launch_bounds__(256, 3) void attn_mfma_kernel(
    const half_t* __restrict__ Qh, const half_t* __restrict__ Kh,
    const half_t* __restrict__ Vt2, half_t* __restrict__ Oh) {
  __shared__ __align__(16) half_t smem[24576];  // 48KB
  half_t* Ks = smem;            // 3 stages x 4096 halfs
  half_t* Vs = smem + 12288;    // 3 stages x 4096 halfs

  const int tid = threadIdx.x;
  const int lane = tid & 63;
  const int wv = tid >> 6;       // 0..3
  const int qp = wv >> 1;        // q-pair: subtiles {2qp, 2qp+1}
  const int half_ = wv & 1;      // k'-half
  const int lr = lane & 15;
  const int lq = lane >> 4;

  int lin = blockIdx.x + 32 * (blockIdx.y + 12 * blockIdx.z);
  lin = (lin & 7) * 96 + (lin >> 3);
  const int q0 = (lin & 31) * 64;
  const int hb = lin >> 5;       // 0..23
  const int h = hb % 12;
  const int b = hb / 12;

  const size_t base = (size_t)b * S * D + h * HD;              // + row*D
  const size_t vtbase = (size_t)(b * H + h) * HD * (size_t)S;  // vt2 head base

  // Q B-fragments for both owned subtiles, scale = (1/8)*log2(e)
  const half_t qscale = (half_t)0.18033688f;
  half8 qf[2][2];
#pragma unroll
  for (int s = 0; s < 2; ++s) {
    const int qw = q0 + (qp * 2 + s) * 16;
#pragma unroll
    for (int c = 0; c < 2; ++c) {
      half8 qv = *reinterpret_cast<const half8*>(
          &Qh[base + (size_t)(qw + lr) * D + c * 32 + lq * 8]);
#pragma unroll
      for (int j = 0; j < 8; ++j) qv[j] = qv[j] * qscale;
      qf[s][c] = qv;
    }
  }

  half8 ones8;
#pragma unroll
  for (int j = 0; j < 8; ++j) ones8[j] = (half_t)1.0f;

  floatx4 o[2][4] = {};
  floatx4 ol[2] = {};

  // 16 DMA groups (8 K + 8 V), 4 per wave.
#define STAGE(soff, kb)                                                        \
  do {                                                                         \
    _Pragma("unroll") for (int gi = 0; gi < 4; ++gi) {                         \
      int g = wv * 4 + gi;                                                     \
      if (g < 8) {                                                             \
        int u = g >> 1, c = g & 1;                                             \
        gl_lds16(                                                              \
            Kh + base + (size_t)((kb) + u * 16 + lr) * D + c * 32 + lq * 8,    \
            Ks + (soff) + g * 512);                                            \
      } else {                                                                 \
        int gv = g - 8;                                                        \
        gl_lds16(Vt2 + vtbase + (size_t)(kb)*64 + gv * 512 + lane * 8,         \
                 Vs + (soff) + gv * 512);                                      \
      }                                                                        \
    }                                                                          \
  } while (0)

  // QK^T of the tile in LDS buffer `co` -> named st regs; V -> named vf regs.
#define QKPHASE(v0, v1, v2, v3, s00, s01, s10, s11)                            \
  do {                                                                         \
    v0 = *reinterpret_cast<const half8*>(                                      \
        &Vs[co + ((0 * 2 + half_) * 64 + lane) * 8]);                          \
    v1 = *reinterpret_cast<const half8*>(                                      \
        &Vs[co + ((1 * 2 + half_) * 64 + lane) * 8]);                          \
    v2 = *reinterpret_cast<const half8*>(                                      \
        &Vs[co + ((2 * 2 + half_) * 64 + lane) * 8]);                          \
    v3 = *reinterpret_cast<const half8*>(                                      \
        &Vs[co + ((3 * 2 + half_) * 64 + lane) * 8]);                          \
    {                                                                          \
      const int u = half_ * 2;                                                 \
      half8 kf0 = *reinterpret_cast<const half8*>(                             \
          &Ks[co + ((u * 2 + 0) * 64 + lane) * 8]);                            \
      half8 kf1 = *reinterpret_cast<const half8*>(                             \
          &Ks[co + ((u * 2 + 1) * 64 + lane) * 8]);                            \
      SETPRIO(1);                                                              \
      floatx4 t0 = {}, t1 = {};                                                \
      t0 = MFMA32(kf0, qf[0][0], t0);                                          \
      t0 = MFMA32(kf1, qf[0][1], t0);                                          \
      t1 = MFMA32(kf0, qf[1][0], t1);                                          \
      t1 = MFMA32(kf1, qf[1][1], t1);                                          \
      SETPRIO(0);                                                              \
      s00 = t0;                                                                \
      s10 = t1;                                                                \
    }                                                                          \
    {                                                                          \
      const int u = half_ * 2 + 1;                                             \
      half8 kf0 = *reinterpret_cast<const half8*>(                             \
          &Ks[co + ((u * 2 + 0) * 64 + lane) * 8]);                            \
      half8 kf1 = *reinterpret_cast<const half8*>(                             \
          &Ks[co + ((u * 2 + 1) * 64 + lane) * 8]);                            \
      SETPRIO(1);                                                              \
      floatx4 t0 = {}, t1 = {};                                                \
      t0 = MFMA32(kf0, qf[0][0], t0);                                          \
      t0 = MFMA32(kf1, qf[0][1], t0);                                          \
      t1 = MFMA32(kf0, qf[1][0], t1);                                          \
      t1 = MFMA32(kf1, qf[1][1], t1);                                          \
      SETPRIO(0);                                                              \
      s01 = t0;                                                                \
      s11 = t1;                                                                \
    }                                                                          \
  } while (0)

  // exp+pack of a PREVIOUS tile's held scores, then its PV accumulation.
#define EXPPV(v0, v1, v2, v3, s00, s01, s10, s11)                              \
  do {                                                                         \
    half8 pv0, pv1;                                                            \
    _Pragma("unroll") for (int j = 0; j < 4; ++j) {                            \
      pv0[j] = (half_t)EXP2F(s00[j]);                                          \
      pv0[4 + j] = (half_t)EXP2F(s01[j]);                                      \
      pv1[j] = (half_t)EXP2F(s10[j]);                                          \
      pv1[4 + j] = (half_t)EXP2F(s11[j]);                                      \
    }                                                                          \
    SETPRIO(1);                                                                \
    o[0][0] = MFMA32(pv0, v0, o[0][0]);                                        \
    o[1][0] = MFMA32(pv1, v0, o[1][0]);                                        \
    o[0][1] = MFMA32(pv0, v1, o[0][1]);                                        \
    o[1][1] = MFMA32(pv1, v1, o[1][1]);                                        \
    o[0][2] = MFMA32(pv0, v2, o[0][2]);                                        \
    o[1][2] = MFMA32(pv1, v2, o[1][2]);                                        \
    o[0][3] = MFMA32(pv0, v3, o[0][3]);                                        \
    o[1][3] = MFMA32(pv1, v3, o[1][3]);                                        \
    ol[0] = MFMA32(pv0, ones8, ol[0]);                                         \
    ol[1] = MFMA32(pv1, ones8, ol[1]);                                         \
    SETPRIO(0);                                                                \
  } while (0)

#define ROT()                                                                  \
  do {                                                                         \
    co += 4096; if (co == 12288) co = 0;                                       \
    so += 4096; if (so == 12288) so = 0;                                       \
  } while (0)

  STAGE(0, 0);
  STAGE(4096, 64);
  SWAIT(4);
  SBAR();

  int co = 0, so = 8192;
  // Named double-buffered pipeline state (NO arrays -> no scratch).
  floatx4 sA00, sA01, sA10, sA11, sB00, sB01, sB10, sB11;
  half8 vA0, vA1, vA2, vA3, vB0, vB1, vB2, vB3;

  // peel tile 0: QK only (no previous tile to finish)
  STAGE(so, 2 * 64);
  QKPHASE(vA0, vA1, vA2, vA3, sA00, sA01, sA10, sA11);
  SWAIT(4);
  SBAR();
  ROT();

  for (int it = 1; it < 31; it += 2) {
    // tile it: QK -> B set; finish tile it-1 from A set
    STAGE(so, (it + 2) * 64);
    QKPHASE(vB0, vB1, vB2, vB3, sB00, sB01, sB10, sB11);
    EXPPV(vA0, vA1, vA2, vA3, sA00, sA01, sA10, sA11);
    SWAIT(4);
    SBAR();
    ROT();
    // tile it+1: QK -> A set; finish tile it from B set
    if (it + 3 < 32) {
      STAGE(so, (it + 3) * 64);
      QKPHASE(vA0, vA1, vA2, vA3, sA00, sA01, sA10, sA11);
      EXPPV(vB0, vB1, vB2, vB3, sB00, sB01, sB10, sB11);
      SWAIT(4);
    } else {
      QKPHASE(vA0, vA1, vA2, vA3, sA00, sA01, sA10, sA11);
      EXPPV(vB0, vB1, vB2, vB3, sB00, sB01, sB10, sB11);
      SWAIT(0);
    }
    SBAR();
    ROT();
  }
  // tile 31: QK from buffer co; finish tiles 30 and 31 (registers only)
  QKPHASE(vB0, vB1, vB2, vB3, sB00, sB01, sB10, sB11);
  EXPPV(vA0, vA1, vA2, vA3, sA00, sA01, sA10, sA11);
  EXPPV(vB0, vB1, vB2, vB3, sB00, sB01, sB10, sB11);
#undef STAGE
#undef QKPHASE
#undef EXPPV
#undef ROT

  // merge k'-halves. Extra barrier first: tile-31's QKPHASE read LDS after
  // the last s_barrier, so deposits must wait for every wave.
  __syncthreads();
  float* red = (float*)smem;  // 20 comps x 260 floats = 20.8KB <= 48KB
  if (half_ == 1) {
#pragma unroll
    for (int s = 0; s < 2; ++s) {
      const int slot = (qp * 2 + s) * 64 + lane;  // 0..255
#pragma unroll
      for (int comp = 0; comp < 16; ++comp)
        red[comp * 260 + slot] = o[s][comp >> 2][comp & 3];
#pragma unroll
      for (int r = 0; r < 4; ++r) red[(16 + r) * 260 + slot] = ol[s][r];
    }
  }
  __syncthreads();
  if (half_ == 0) {
#pragma unroll
    for (int s = 0; s < 2; ++s) {
      const int slot = (qp * 2 + s) * 64 + lane;
      const int qw = q0 + (qp * 2 + s) * 16;
      float linv[4];
#pragma unroll
      for (int r = 0; r < 4; ++r)
        linv[r] = 1.0f / (ol[s][r] + red[(16 + r) * 260 + slot]);
#pragma unroll
      for (int ud = 0; ud < 4; ++ud) {
#pragma unroll
        for (int r = 0; r < 4; ++r) {
          float ov = o[s][ud][r] + red[(ud * 4 + r) * 260 + slot];
          int row = qw + lq * 4 + r;
          int col = h * HD + ud * 16 + lr;
          Oh[(size_t)(b * S + row) * D + col] = (half_t)(ov * linv[r]);
        }
      }
    }
  }
}

// ---------------------------------------------------------------------------
// Launch
// ---------------------------------------------------------------------------
extern "C" void kernel_launch(void* const* d_in, const int* in_sizes, int n_in,
                              void* d_out, int out_size, void* d_ws,
                              size_t ws_size, hipStream_t stream) {
  const float* query = (const float*)d_in[0];
  const float* key   = (const float*)d_in[1];
  const float* value = (const float*)d_in[2];
  const float* Wq = (const float*)d_in[3];
  const float* bq = (const float*)d_in[4];
  const float* Aq = (const float*)d_in[5];
  const float* Wk = (const float*)d_in[6];
  const float* bk = (const float*)d_in[7];
  const float* Ak = (const float*)d_in[8];
  const float* Wv = (const float*)d_in[9];
  const float* bv = (const float*)d_in[10];
  const float* Av = (const float*)d_in[11];
  const float* Wo = (const float*)d_in[12];
  const float* bo = (const float*)d_in[13];
  float* out = (float*)d_out;

  half_t* hw = (half_t*)d_ws;
  const size_t XSZ = (size_t)NROWS * D;  // 3145728
  const size_t MSZ = (size_t)D * D;      // 589824
  half_t* xq = hw;              // converted inputs (fp16)
  half_t* xk = xq + XSZ;
  half_t* xv = xk + XSZ;
  half_t* qh = xv + XSZ;        // Q projection [n][D]
  half_t* kh = qh + XSZ;        // K projection [n][D]
  half_t* vt = kh + XSZ;        // V projection, vt2 tiled-fragment layout
  half_t* ab = vt + XSZ;        // attention output [n][D]
  half_t* Mq = ab + XSZ;
  half_t* Mk = Mq + MSZ;
  half_t* Mv = Mk + MSZ;
  half_t* Mo = Mv + MSZ;

  prep_kernel<<<3024, 256, 0, stream>>>(query, key, value, xq, xk, xv, Wq, Aq,
                                        Wk, Ak, Wv, Av, Wo, Mq, Mk, Mv, Mo);

  dim3 gq(D / 128, NROWS / 128, 3);  // (6, 32, 3) = 576 blocks
  gemm_qkv_kernel<<<gq, 256, 0, stream>>>(xq, xk, xv, Mq, Mk, Mv, bq, bk, bv,
                                          qh, kh, vt);

  dim3 ga(S / 64, H, B_);  // (32, 12, 2) blocks of 256 threads
  attn_mfma_kernel<<<ga, 256, 0, stream>>>(qh, kh, vt, ab);

  dim3 go(D / 64, NROWS / 64, 1);  // (12, 64) = 768 blocks
  gemm_o_kernel<<<go, 256, 0, stream>>>(ab, Mo, bo, out);
}

// Round 8
// 199.848 us; speedup vs baseline: 1.3549x; 1.3549x over previous
//
#include <hip/hip_runtime.h>
#include <math.h>
#include <stdint.h>

// Problem constants
#define D 768
#define S 2048
#define B_ 2
#define NROWS 4096   // B_*S
#define H 12
#define HD 64
#define R_ 16

typedef _Float16 half_t;
typedef _Float16 half8 __attribute__((ext_vector_type(8)));
typedef _Float16 half4 __attribute__((ext_vector_type(4)));
typedef float floatx4 __attribute__((ext_vector_type(4)));

#define MFMA32(a, b, c) __builtin_amdgcn_mfma_f32_16x16x32_f16(a, b, c, 0, 0, 0)
#define EXP2F(x) __builtin_amdgcn_exp2f(x)

#define SWAIT(N) __builtin_amdgcn_s_waitcnt(0x0F70 | (N))
#define SBAR() __builtin_amdgcn_s_barrier()
#define SETPRIO(N) __builtin_amdgcn_s_setprio(N)

// global -> LDS async DMA, 16B per lane; lane i lands at base + 16*i.
__device__ __forceinline__ void gl_lds16(const void* gp, half_t* lp) {
  __builtin_amdgcn_global_load_lds(
      (const __attribute__((address_space(1))) void*)(gp),
      (__attribute__((address_space(3))) void*)(lp), 16, 0, 0);
}

// V^T tiled-fragment layout ("vt2"): per head bh = b*H+h, per 64-token block
// kb (32 blocks): 4096 halfs = groups (ud 0..3, h2 0..1) x 512 halfs; lane
// (lq,lr) holds 8 halfs: V[kb*64+32*h2+lq*4+{0..3}][ud*16+lr] ++
//                        V[kb*64+32*h2+16+lq*4+{0..3}][ud*16+lr].

// ---------------------------------------------------------------------------
// Fused prep (round-6 verified): convert q,k,v + Wo; LDS-staged M-build.
// ---------------------------------------------------------------------------
__global__ __launch_bounds__(256) void prep_kernel(
    const float* __restrict__ q, const float* __restrict__ k,
    const float* __restrict__ v, half_t* __restrict__ xq,
    half_t* __restrict__ xk, half_t* __restrict__ xv,
    const float* __restrict__ Wq, const float* __restrict__ Aq,
    const float* __restrict__ Wk, const float* __restrict__ Ak,
    const float* __restrict__ Wv, const float* __restrict__ Av,
    const float* __restrict__ Wo, half_t* __restrict__ Mq,
    half_t* __restrict__ Mk, half_t* __restrict__ Mv,
    half_t* __restrict__ Mo) {
  __shared__ float4 As[3072];  // 48KB (used by M-build blocks only)
  const int bid = blockIdx.x;
  const int tid = threadIdx.x;

  if (bid < 2304) {
    const int y = bid / 768;
    const float* x = (y == 0) ? q : (y == 1) ? k : v;
    half_t* o = (y == 0) ? xq : (y == 1) ? xk : xv;
    const int base = (bid - y * 768) * 4096;
#pragma unroll
    for (int c = 0; c < 4; ++c) {
      int i = base + (tid + 256 * c) * 4;
      float4 vv = *reinterpret_cast<const float4*>(x + i);
      half_t tmp[4] = {(half_t)vv.x, (half_t)vv.y, (half_t)vv.z, (half_t)vv.w};
      *reinterpret_cast<uint64_t*>(o + i) = *reinterpret_cast<uint64_t*>(tmp);
    }
  } else if (bid < 2448) {
    const int base = (bid - 2304) * 4096;
#pragma unroll
    for (int c = 0; c < 4; ++c) {
      int i = base + (tid + 256 * c) * 4;
      float4 vv = *reinterpret_cast<const float4*>(Wo + i);
      half_t tmp[4] = {(half_t)vv.x, (half_t)vv.y, (half_t)vv.z, (half_t)vv.w};
      *reinterpret_cast<uint64_t*>(Mo + i) = *reinterpret_cast<uint64_t*>(tmp);
    }
  } else {
    const int u = bid - 2448;
    const int y = u / 192;           // 0..2 -> q,k,v
    const int jb = u - y * 192;      // j-band
    const float* W = (y == 0) ? Wq : (y == 1) ? Wk : Wv;
    const float* A = (y == 0) ? Aq : (y == 1) ? Ak : Av;
    half_t* M = (y == 0) ? Mq : (y == 1) ? Mk : Mv;

    // Stage A[768][16] f32 into LDS, coalesced.
#pragma unroll
    for (int c = 0; c < 12; ++c)
      As[tid + 256 * c] =
          *reinterpret_cast<const float4*>(A + (tid + 256 * c) * 4);
    __syncthreads();

    const int j0 = jb * 4;
    float4 aj[4][4];
#pragma unroll
    for (int jj = 0; jj < 4; ++jj)
#pragma unroll
      for (int qq = 0; qq < 4; ++qq) aj[jj][qq] = As[(j0 + jj) * 4 + qq];

#pragma unroll
    for (int c = 0; c < 3; ++c) {
      const int kk = tid + 256 * c;
      float4 ak[4];
#pragma unroll
      for (int qq = 0; qq < 4; ++qq) ak[qq] = As[kk * 4 + qq];
#pragma unroll
      for (int jj = 0; jj < 4; ++jj) {
        float s = 0.f;
#pragma unroll
        for (int qq = 0; qq < 4; ++qq)
          s += ak[qq].x * aj[jj][qq].x + ak[qq].y * aj[jj][qq].y +
               ak[qq].z * aj[jj][qq].z + ak[qq].w * aj[jj][qq].w;
        const int idx = (j0 + jj) * D + kk;
        M[idx] = (half_t)(W[idx] + 4.0f * s);
      }
    }
  }
}

// ---------------------------------------------------------------------------
// QKV GEMM (fp16 in/out): C[n][j] = sum_k X[n][k]*Mh[j][k] + bias[j].
// 128x96 tile -> grid 8 x 32 x 3 = 768 blocks = EXACTLY 3 blocks/CU
// (previous 128x128 gave 576 blocks: 64 CUs carried 3 while 192 carried 2
// -> makespan 3w vs 2.25w average = 25% structural waste).
// 4 waves (2x2: 64 rows x 48 cols each), BK=32, 3-stage DMA pipeline
// (42KB LDS), raw barrier + per-wave counted vmcnt (waves 0,1 issue 4 DMA
// groups/stage -> SWAIT(4); waves 2,3 issue 3 -> SWAIT(3), selected via
// readfirstlane so the scalar s_waitcnt isn't dual-path predicated).
// 12 MFMA : 7 b128-reads per wave-iter. XCD-chunked swizzle (768 = 8x96).
// z==2 writes V output in vt2 layout via direct coalesced half4 stores
// (gc-general: 96-wide tiles crossing head boundaries handled by hh/ud).
// ---------------------------------------------------------------------------
__global__ __launch_bounds__(256) void gemm_qkv_kernel(
    const half_t* __restrict__ x0, const half_t* __restrict__ x1,
    const half_t* __restrict__ x2, const half_t* __restrict__ m0,
    const half_t* __restrict__ m1, const half_t* __restrict__ m2,
    const float* __restrict__ b0, const float* __restrict__ b1,
    const float* __restrict__ b2, half_t* __restrict__ o0,
    half_t* __restrict__ o1, half_t* __restrict__ o2) {
  constexpr int AG = 8;        // A groups (128 rows x 32 k)
  constexpr int G = 14;        // + 6 B groups (96 cols x 32 k)
  constexpr int PB = G * 512;  // 7168 halfs = 14KB per stage
  __shared__ __align__(16) half_t smem[3 * PB];  // 42KB

  // Bijective XCD-chunk swizzle: 768 blocks -> each XCD owns 96 contiguous.
  int lin = blockIdx.x + 8 * (blockIdx.y + 32 * blockIdx.z);
  lin = (lin & 7) * 96 + (lin >> 3);
  const int z = lin / 256;
  const int rem = lin - z * 256;
  const int by = rem >> 3;
  const int bx = rem & 7;

  const half_t* X = (z == 0) ? x0 : (z == 1) ? x1 : x2;
  const half_t* M = (z == 0) ? m0 : (z == 1) ? m1 : m2;
  const float* bias = (z == 0) ? b0 : (z == 1) ? b1 : b2;
  half_t* Out = (z == 0) ? o0 : (z == 1) ? o1 : o2;

  const int tid = threadIdx.x;
  const int lane = tid & 63;
  const int wv = tid >> 6;
  const int lr = lane & 15;
  const int lq = lane >> 4;
  const int row0 = by * 128;
  const int j0 = bx * 96;
  const int wr = wv >> 1;  // wave row 0..1
  const int wc = wv & 1;   // wave col 0..1
  // wave-uniform scalar: 1 if this wave issues 4 DMA groups, else 3
  const int heavy = __builtin_amdgcn_readfirstlane(wv < 2 ? 1 : 0);

  floatx4 acc[4][3] = {};

  // DMA group g = wv + 4*gi: waves 0,1 -> {0,4,8,12},{1,5,9,13} (4 each);
  // waves 2,3 -> {2,6,10},{3,7,11} (3 each; g=14,15 skipped).
#define GSTAGE(soff, k0)                                                      \
  do {                                                                        \
    _Pragma("unroll") for (int gi = 0; gi < 4; ++gi) {                        \
      int g = wv + gi * 4;                                                    \
      if (g < AG) {                                                           \
        gl_lds16(X + (size_t)(row0 + g * 16 + lr) * D + (k0) + lq * 8,        \
                 smem + (soff) + g * 512);                                    \
      } else if (g < G) {                                                     \
        gl_lds16(M + (size_t)(j0 + (g - AG) * 16 + lr) * D + (k0) + lq * 8,   \
                 smem + (soff) + g * 512);                                    \
      }                                                                       \
    }                                                                         \
  } while (0)

#define QWAIT()                                                               \
  do {                                                                        \
    if (heavy) SWAIT(4); else SWAIT(3);                                       \
  } while (0)

  GSTAGE(0, 0);
  GSTAGE(PB, 32);
  QWAIT();
  SBAR();

  int co = 0, so = 2 * PB;
  for (int it = 0; it < D / 32; ++it) {
    if (it + 2 < D / 32) GSTAGE(so, (it + 2) * 32);
    const half_t* Ab = smem + co;
    const half_t* Bb = Ab + AG * 512;
    half8 af[4], bf[3];
#pragma unroll
    for (int t = 0; t < 4; ++t)
      af[t] = *reinterpret_cast<const half8*>(
          &Ab[((wr * 4 + t) * 64 + lane) * 8]);
#pragma unroll
    for (int u = 0; u < 3; ++u)
      bf[u] = *reinterpret_cast<const half8*>(
          &Bb[((wc * 3 + u) * 64 + lane) * 8]);
#pragma unroll
    for (int t = 0; t < 4; ++t)
#pragma unroll
      for (int u = 0; u < 3; ++u) acc[t][u] = MFMA32(af[t], bf[u], acc[t][u]);
    if (it + 2 < D / 32) QWAIT(); else SWAIT(0);
    SBAR();
    co += PB; if (co == 3 * PB) co = 0;
    so += PB; if (so == 3 * PB) so = 0;
  }
#undef GSTAGE
#undef QWAIT

  float bv[3];
#pragma unroll
  for (int u = 0; u < 3; ++u) bv[u] = bias[j0 + (wc * 3 + u) * 16 + lr];

  if (z == 2) {
    // Direct vt2 stores from registers. Rows span 2 kb-blocks: kb = wr.
    const int bb = row0 >> 11;
    const int kb0 = (row0 & 2047) >> 6;
#pragma unroll
    for (int t = 0; t < 4; ++t) {
#pragma unroll
      for (int u = 0; u < 3; ++u) {
        int gc = j0 + (wc * 3 + u) * 16 + lr;
        int hh = gc >> 6;
        int ud = (gc & 63) >> 4;
        half4 hv;
#pragma unroll
        for (int r = 0; r < 4; ++r) hv[r] = (half_t)(acc[t][u][r] + bv[u]);
        size_t addr = ((size_t)(bb * H + hh) * HD) * S +
                      (size_t)(kb0 + wr) * 4096 +
                      (ud * 2 + ((t >> 1) & 1)) * 512 + lane * 8 + (t & 1) * 4;
        *reinterpret_cast<half4*>(&Out[addr]) = hv;
      }
    }
    return;
  }

#pragma unroll
  for (int t = 0; t < 4; ++t) {
#pragma unroll
    for (int u = 0; u < 3; ++u) {
#pragma unroll
      for (int r = 0; r < 4; ++r) {
        int gr = row0 + (wr * 4 + t) * 16 + lq * 4 + r;
        int gc = j0 + (wc * 3 + u) * 16 + lr;
        Out[(size_t)gr * D + gc] = (half_t)(acc[t][u][r] + bv[u]);
      }
    }
  }
}

// ---------------------------------------------------------------------------
// Out-projection GEMM (fp16 in, fp32 out): 64x64 tile, 4 waves (2x2),
// 3-stage DMA pipeline (48KB LDS), raw barrier + vmcnt(4) per iter.
// + XCD-chunked swizzle (768 = 8 x 96). 768 blocks = exactly 3/CU.
// ---------------------------------------------------------------------------
__global__ __launch_bounds__(256) void gemm_o_kernel(
    const half_t* __restrict__ Xh, const half_t* __restrict__ M,
    const float* __restrict__ bias, float* __restrict__ Out) {
  constexpr int AG = 8;        // A groups (64 rows)
  constexpr int G = 16;        // + 8 B groups (64 cols)
  constexpr int PB = G * 512;  // 8192 halfs = 16KB per stage
  __shared__ __align__(16) half_t smem[3 * PB];  // 48KB

  int lin = blockIdx.x + 12 * blockIdx.y;
  lin = (lin & 7) * 96 + (lin >> 3);
  const int bx = lin % 12;
  const int byy = lin / 12;

  const int tid = threadIdx.x;
  const int lane = tid & 63;
  const int wv = tid >> 6;
  const int lr = lane & 15;
  const int lq = lane >> 4;
  const int row0 = byy * 64;
  const int j0 = bx * 64;
  const int wr = wv >> 1;  // wave row 0..1
  const int wc = wv & 1;   // wave col 0..1

  floatx4 acc[2][2] = {};

#define GSTAGE(soff, k0)                                                       \
  do {                                                                         \
    _Pragma("unroll") for (int gi = 0; gi < 4; ++gi) {                         \
      int g = wv * 4 + gi;                                                     \
      if (g < AG) {                                                            \
        int t = g >> 1, c = g & 1;                                             \
        gl_lds16(                                                              \
            Xh + (size_t)(row0 + t * 16 + lr) * D + (k0) + c * 32 + lq * 8,    \
            smem + (soff) + g * 512);                                          \
      } else {                                                                 \
        int g2 = g - AG;                                                       \
        int u = g2 >> 1, c = g2 & 1;                                           \
        gl_lds16(                                                              \
            M + (size_t)(j0 + u * 16 + lr) * D + (k0) + c * 32 + lq * 8,       \
            smem + (soff) + AG * 512 + g2 * 512);                              \
      }                                                                        \
    }                                                                          \
  } while (0)

  GSTAGE(0, 0);
  GSTAGE(PB, 64);
  SWAIT(4);
  SBAR();

  int co = 0, so = 2 * PB;
  for (int it = 0; it < D / 64; ++it) {
    if (it + 2 < D / 64) GSTAGE(so, (it + 2) * 64);
    const half_t* Ab = smem + co;
    const half_t* Bb = Ab + AG * 512;
#pragma unroll
    for (int c = 0; c < 2; ++c) {
      half8 af[2], bf[2];
#pragma unroll
      for (int t = 0; t < 2; ++t)
        af[t] = *reinterpret_cast<const half8*>(
            &Ab[(((wr * 2 + t) * 2 + c) * 64 + lane) * 8]);
#pragma unroll
      for (int u = 0; u < 2; ++u)
        bf[u] = *reinterpret_cast<const half8*>(
            &Bb[(((wc * 2 + u) * 2 + c) * 64 + lane) * 8]);
#pragma unroll
      for (int t = 0; t < 2; ++t)
#pragma unroll
        for (int u = 0; u < 2; ++u) acc[t][u] = MFMA32(af[t], bf[u], acc[t][u]);
    }
    if (it + 2 < D / 64) SWAIT(4); else SWAIT(0);
    SBAR();
    co += PB; if (co == 3 * PB) co = 0;
    so += PB; if (so == 3 * PB) so = 0;
  }
#undef GSTAGE

  float bv[2];
#pragma unroll
  for (int u = 0; u < 2; ++u) bv[u] = bias[j0 + (wc * 2 + u) * 16 + lr];
#pragma unroll
  for (int t = 0; t < 2; ++t) {
#pragma unroll
    for (int u = 0; u < 2; ++u) {
#pragma unroll
      for (int r = 0; r < 4; ++r) {
        int gr = row0 + (wr * 2 + t) * 16 + lq * 4 + r;
        int gc = j0 + (wc * 2 + u) * 16 + lr;
        Out[(size_t)gr * D + gc] = acc[t][u][r] + bv[u];
      }
    }
  }
}

// ---------------------------------------------------------------------------
// Flash attention, in-block split-K (round-2 proven structure, 43.5us).
// 256 threads (4 waves), 64 q-rows/block. Wave w: q-PAIR qp=w>>1,
// k'-half = w&1. 3-stage DMA pipeline (48KB LDS), raw barrier + counted
// vmcnt(4) per iter. s_setprio(1) around MFMA clusters.
// Partials additive; k'-half merge via LDS at the end.
// XCD-chunked swizzle (768 = 8 x 96): each XCD owns 3 whole (b,h) heads.
// ---------------------------------------------------------------------------
__global__ __launch_bounds__(256, 3) void attn_mfma_kernel(
    const half_t* __restrict__ Qh, const half_t* __restrict__ Kh,
    const half_t* __restrict__ Vt2, half_t* __restrict__ Oh) {
  __shared__ __align__(16) half_t smem[24576];  // 48KB
  half_t* Ks = smem;            // 3 stages x 4096 halfs
  half_t* Vs = smem + 12288;    // 3 stages x 4096 halfs

  const int tid = threadIdx.x;
  const int lane = tid & 63;
  const int wv = tid >> 6;       // 0..3
  const int qp = wv >> 1;        // q-pair: subtiles {2qp, 2qp+1}
  const int half_ = wv & 1;      // k'-half
  const int lr = lane & 15;
  const int lq = lane >> 4;

  int lin = blockIdx.x + 32 * (blockIdx.y + 12 * blockIdx.z);
  lin = (lin & 7) * 96 + (lin >> 3);
  const int q0 = (lin & 31) * 64;
  const int hb = lin >> 5;       // 0..23
  const int h = hb % 12;
  const int b = hb / 12;

  const size_t base = (size_t)b * S * D + h * HD;              // + row*D
  const size_t vtbase = (size_t)(b * H + h) * HD * (size_t)S;  // vt2 head base

  // Q B-fragments for both owned subtiles, scale = (1/8)*log2(e)
  const half_t qscale = (half_t)0.18033688f;
  half8 qf[2][2];
#pragma unroll
  for (int s = 0; s < 2; ++s) {
    const int qw = q0 + (qp * 2 + s) * 16;
#pragma unroll
    for (int c = 0; c < 2; ++c) {
      half8 qv = *reinterpret_cast<const half8*>(
          &Qh[base + (size_t)(qw + lr) * D + c * 32 + lq * 8]);
#pragma unroll
      for (int j = 0; j < 8; ++j) qv[j] = qv[j] * qscale;
      qf[s][c] = qv;
    }
  }

  half8 ones8;
#pragma unroll
  for (int j = 0; j < 8; ++j) ones8[j] = (half_t)1.0f;

  floatx4 o[2][4] = {};
  floatx4 ol[2] = {};

  // 16 DMA groups (8 K + 8 V), 4 per wave.
#define STAGE(soff, kb)                                                        \
  do {                                                                         \
    _Pragma("unroll") for (int gi = 0; gi < 4; ++gi) {                         \
      int g = wv * 4 + gi;                                                     \
      if (g < 8) {                                                             \
        int u = g >> 1, c = g & 1;                                             \
        gl_lds16(                                                              \
            Kh + base + (size_t)((kb) + u * 16 + lr) * D + c * 32 + lq * 8,    \
            Ks + (soff) + g * 512);                                            \
      } else {                                                                 \
        int gv = g - 8;                                                        \
        gl_lds16(Vt2 + vtbase + (size_t)(kb)*64 + gv * 512 + lane * 8,         \
                 Vs + (soff) + gv * 512);                                      \
      }                                                                        \
    }                                                                          \
  } while (0)

  STAGE(0, 0);
  STAGE(4096, 64);
  SWAIT(4);
  SBAR();

  int co = 0, so = 8192;
  for (int it = 0; it < S / 64; ++it) {
    if (it + 2 < S / 64) STAGE(so, (it + 2) * 64);

    // S^T for both u-subtiles of this wave's k'-half, for BOTH q-subtiles.
    half8 pv[2];
#pragma unroll
    for (int ui = 0; ui < 2; ++ui) {
      const int u = half_ * 2 + ui;
      half8 kf0 = *reinterpret_cast<const half8*>(
          &Ks[co + ((u * 2 + 0) * 64 + lane) * 8]);
      half8 kf1 = *reinterpret_cast<const half8*>(
          &Ks[co + ((u * 2 + 1) * 64 + lane) * 8]);
      SETPRIO(1);
      floatx4 st0 = {}, st1 = {};
      st0 = MFMA32(kf0, qf[0][0], st0);
      st0 = MFMA32(kf1, qf[0][1], st0);
      st1 = MFMA32(kf0, qf[1][0], st1);
      st1 = MFMA32(kf1, qf[1][1], st1);
      SETPRIO(0);
#pragma unroll
      for (int j = 0; j < 4; ++j) {
        pv[0][4 * ui + j] = (half_t)EXP2F(st0[j]);
        pv[1][4 * ui + j] = (half_t)EXP2F(st1[j]);
      }
    }
    // PV: one b128 per ud supplies the full K=32 B-fragment, reused by
    // both q-subtiles' MFMAs.
    SETPRIO(1);
#pragma unroll
    for (int ud = 0; ud < 4; ++ud) {
      half8 vf8 = *reinterpret_cast<const half8*>(
          &Vs[co + ((ud * 2 + half_) * 64 + lane) * 8]);
      o[0][ud] = MFMA32(pv[0], vf8, o[0][ud]);
      o[1][ud] = MFMA32(pv[1], vf8, o[1][ud]);
    }
    ol[0] = MFMA32(pv[0], ones8, ol[0]);
    ol[1] = MFMA32(pv[1], ones8, ol[1]);
    SETPRIO(0);

    if (it + 2 < S / 64) SWAIT(4); else SWAIT(0);
    SBAR();
    co += 4096; if (co == 12288) co = 0;
    so += 4096; if (so == 12288) so = 0;
  }
#undef STAGE

  // merge k'-halves: waves half_=1 deposit partials (SoA, stride 260),
  // half_=0 reduce. Each wave handles its 2 q-subtiles.
  float* red = (float*)smem;  // 20 comps x 260 floats = 20.8KB <= 48KB
  if (half_ == 1) {
#pragma unroll
    for (int s = 0; s < 2; ++s) {
      const int slot = (qp * 2 + s) * 64 + lane;  // 0..255
#pragma unroll
      for (int comp = 0; comp < 16; ++comp)
        red[comp * 260 + slot] = o[s][comp >> 2][comp & 3];
#pragma unroll
      for (int r = 0; r < 4; ++r) red[(16 + r) * 260 + slot] = ol[s][r];
    }
  }
  __syncthreads();
  if (half_ == 0) {
#pragma unroll
    for (int s = 0; s < 2; ++s) {
      const int slot = (qp * 2 + s) * 64 + lane;
      const int qw = q0 + (qp * 2 + s) * 16;
      float linv[4];
#pragma unroll
      for (int r = 0; r < 4; ++r)
        linv[r] = 1.0f / (ol[s][r] + red[(16 + r) * 260 + slot]);
#pragma unroll
      for (int ud = 0; ud < 4; ++ud) {
#pragma unroll
        for (int r = 0; r < 4; ++r) {
          float ov = o[s][ud][r] + red[(ud * 4 + r) * 260 + slot];
          int row = qw + lq * 4 + r;
          int col = h * HD + ud * 16 + lr;
          Oh[(size_t)(b * S + row) * D + col] = (half_t)(ov * linv[r]);
        }
      }
    }
  }
}

// ---------------------------------------------------------------------------
// Launch
// ---------------------------------------------------------------------------
extern "C" void kernel_launch(void* const* d_in, const int* in_sizes, int n_in,
                              void* d_out, int out_size, void* d_ws,
                              size_t ws_size, hipStream_t stream) {
  const float* query = (const float*)d_in[0];
  const float* key   = (const float*)d_in[1];
  const float* value = (const float*)d_in[2];
  const float* Wq = (const float*)d_in[3];
  const float* bq = (const float*)d_in[4];
  const float* Aq = (const float*)d_in[5];
  const float* Wk = (const float*)d_in[6];
  const float* bk = (const float*)d_in[7];
  const float* Ak = (const float*)d_in[8];
  const float* Wv = (const float*)d_in[9];
  const float* bv = (const float*)d_in[10];
  const float* Av = (const float*)d_in[11];
  const float* Wo = (const float*)d_in[12];
  const float* bo = (const float*)d_in[13];
  float* out = (float*)d_out;

  half_t* hw = (half_t*)d_ws;
  const size_t XSZ = (size_t)NROWS * D;  // 3145728
  const size_t MSZ = (size_t)D * D;      // 589824
  half_t* xq = hw;              // converted inputs (fp16)
  half_t* xk = xq + XSZ;
  half_t* xv = xk + XSZ;
  half_t* qh = xv + XSZ;        // Q projection [n][D]
  half_t* kh = qh + XSZ;        // K projection [n][D]
  half_t* vt = kh + XSZ;        // V projection, vt2 tiled-fragment layout
  half_t* ab = vt + XSZ;        // attention output [n][D]
  half_t* Mq = ab + XSZ;
  half_t* Mk = Mq + MSZ;
  half_t* Mv = Mk + MSZ;
  half_t* Mo = Mv + MSZ;

  prep_kernel<<<3024, 256, 0, stream>>>(query, key, value, xq, xk, xv, Wq, Aq,
                                        Wk, Ak, Wv, Av, Wo, Mq, Mk, Mv, Mo);

  dim3 gq(D / 96, NROWS / 128, 3);  // (8, 32, 3) = 768 blocks, 3/CU exact
  gemm_qkv_kernel<<<gq, 256, 0, stream>>>(xq, xk, xv, Mq, Mk, Mv, bq, bk, bv,
                                          qh, kh, vt);

  dim3 ga(S / 64, H, B_);  // (32, 12, 2) blocks of 256 threads
  attn_mfma_kernel<<<ga, 256, 0, stream>>>(qh, kh, vt, ab);

  dim3 go(D / 64, NROWS / 64, 1);  // (12, 64) = 768 blocks
  gemm_o_kernel<<<go, 256, 0, stream>>>(ab, Mo, bo, out);
}